// Round 5
// baseline (466.490 us; speedup 1.0000x reference)
//
#include <hip/hip_runtime.h>
#include <hip/hip_bf16.h>

// B=2, S=4096, E=1024 attention + QKV projections, all-fp16 MFMA pipeline:
//   cvt_mask  fp32->fp16 q,k,v,W* + mask -> 2MB bitmask (in d_out head)
//   gemm512   z=2: q/k projections, 256x256, R3 half-K-ring core (CONTROL)
//   gemm256   v^T projection, 256x128 4-phase core
//   gemm_qk   256x256, depth-3 template core (EXPERIMENT), XCD-remapped
//   gemm_pv   256x128 tile, 4-phase core, K=4096: O = (S' vt) / l
//
// Round-5: core8x ledger fixed to the verified template's prefetch depth:
// 3 half-tiles in flight, vmcnt(6) at p3/p7 (R4 kept only 2 -> waits
// retired loads issued 1 phase earlier => stalled under HBM latency).
// gemm512 runs the R3 ring core as a same-shape control for A/B.

typedef _Float16 f16_t;
typedef _Float16 f16x8 __attribute__((ext_vector_type(8)));
typedef float f32x4 __attribute__((ext_vector_type(4)));
typedef unsigned long long u64;
typedef unsigned int uint;

union PackH8 { f16x8 v; f16_t e[8]; };

__device__ __forceinline__ f32x4 mfma_f16(f16x8 a, f16x8 b, f32x4 c) {
  return __builtin_amdgcn_mfma_f32_16x16x32_f16(a, b, c, 0, 0, 0);
}

__device__ __forceinline__ void cp16(const f16_t* g, f16_t* l) {
  __builtin_amdgcn_global_load_lds(
      (const __attribute__((address_space(1))) unsigned int*)g,
      (__attribute__((address_space(3))) unsigned int*)l, 16, 0, 0);
}

// ---- fp32 -> fp16 bulk convert (y=0..5) + mask bitpack (y=6) ----
__global__ __launch_bounds__(256) void cvt_mask(
    const float* __restrict__ q, const float* __restrict__ k,
    const float* __restrict__ v, const float* __restrict__ wq,
    const float* __restrict__ wk, const float* __restrict__ wv,
    const int* __restrict__ mask,
    f16_t* __restrict__ xq, f16_t* __restrict__ xk, f16_t* __restrict__ xv,
    f16_t* __restrict__ wqh, f16_t* __restrict__ wkh, f16_t* __restrict__ wvh,
    u64* __restrict__ mb) {
  if (blockIdx.y == 6) {
    const int lane = threadIdx.x & 63;
    int wid = blockIdx.x * 4 + (threadIdx.x >> 6);
    for (int w = wid; w < 262144; w += 16384) {
      const int pred = mask[(size_t)w * 64 + lane] != 0;
      u64 b = __ballot(pred);
      if (lane == 0) mb[w] = b;
    }
    return;
  }
  const float* src; f16_t* dst; size_t n;
  switch (blockIdx.y) {
    case 0: src = q;  dst = xq;  n = 8388608; break;
    case 1: src = k;  dst = xk;  n = 8388608; break;
    case 2: src = v;  dst = xv;  n = 8388608; break;
    case 3: src = wq; dst = wqh; n = 1048576; break;
    case 4: src = wk; dst = wkh; n = 1048576; break;
    default: src = wv; dst = wvh; n = 1048576; break;
  }
  size_t i = ((size_t)blockIdx.x * 256 + threadIdx.x) * 8;
  if (i >= n) return;
  float4 a = *(const float4*)(src + i);
  float4 b = *(const float4*)(src + i + 4);
  PackH8 p;
  p.e[0] = (f16_t)a.x; p.e[1] = (f16_t)a.y; p.e[2] = (f16_t)a.z; p.e[3] = (f16_t)a.w;
  p.e[4] = (f16_t)b.x; p.e[5] = (f16_t)b.y; p.e[6] = (f16_t)b.z; p.e[7] = (f16_t)b.w;
  *(f16x8*)(dst + i) = p.v;
}

#define BARR { asm volatile("" ::: "memory"); __builtin_amdgcn_s_barrier(); }
#define VM0 asm volatile("s_waitcnt vmcnt(0)" ::: "memory");
#define VM3 asm volatile("s_waitcnt vmcnt(3)" ::: "memory");
#define VM4 asm volatile("s_waitcnt vmcnt(4)" ::: "memory");
#define VM6 asm volatile("s_waitcnt vmcnt(6)" ::: "memory");

// ---- depth-3 template 8-phase 256x256 GEMM core (512 thr, 2M x 4N waves) --
// LDS per matrix: [2 buf][2 slab(HT)][128 rows][64 k] f16 (HT = 16KB, 2 cp16).
// Reads: p0: A0+B0, p1: B1, p2: A1, p3: -  (buf0; p4-7 same on buf1).
// MFMA:  p0:(0,0) p1:(0,1) p2:(1,0) p3:(1,1) on regs read SAME phase
//        (barrier between; compiler inserts counted lgkmcnt).
// Stages (iter i; kA=t0+1, kB=t0+2, kC=t0+3 tiles):
//   p0: b1.A1(kA)  p1: b0.A0(kB)  p2: b0.B0(kB)  p3: b0.B1(kB) +VM6
//   p4: b0.A1(kB)  p5: b1.A0(kC)  p6: b1.B0(kC)  p7: b1.B1(kC) +VM6
// RAW FIFO (2 loads/HT; VM6 leaves 3 HT): entering iter outstanding =
// [b1.A0,B0,B1](kA)=6. p3-end: 14 -> VM6 confirms b1 all 4 HT (incl. A1
// staged p0, 3-phase lead) before p4 reads. p7-end: confirms b0(kB) before
// next p0. WAR: each HT staged >=1 barrier after its only read phase
// (A0: rd p0/st p1; B0: p0/p2; B1: p1/p3; A1: p2/p4; b1 shifted +4;
// b1.A1: rd p6 prev iter / st p0). Prologue: 7 HT {b0 x4, b1.A0,B0,B1},
// VM6 confirms b0. Peel: only p0's b1.A1(K-64) stage remains; VM0 at p3.
__device__ __forceinline__ void core8x(
    const f16_t* __restrict__ Ab, const f16_t* __restrict__ Bb,
    int m0, int n0, int K, int iters, f32x4 (&acc)[8][4]) {
  __shared__ f16_t lA[32768];
  __shared__ f16_t lB[32768];

  const int tid = threadIdx.x;
  const int w = tid >> 6, lane = tid & 63;
  const int quad = lane >> 4, l15 = lane & 15;
  const int wm2 = w >> 2, wn4 = w & 3;

  // staging: thread t covers HT bytes t*16 (+8192B for load 2). local row
  // tr=t/8, physical col-group c=t&7 holds logical k-group c^(tr&7).
  const int tr = tid >> 3;
  const int sgt = (tid & 7) ^ (tr & 7);
  const uint aoff = (uint)(m0 + tr) * K + sgt * 8;
  const uint boff = (uint)(n0 + tr + ((tr >> 5) << 5)) * K + sgt * 8;
  const uint l2off = (uint)128 * K;   // +128 global rows for load 2
  const int wq = w * 512;             // per-wave linear LDS dest (elems)

  // fragment read offsets (elems within a slab): row*64 + swizzled-group*8
  int ar[4][2], br[2][2];
#pragma unroll
  for (int mi = 0; mi < 4; mi++)
#pragma unroll
    for (int ks = 0; ks < 2; ks++)
      ar[mi][ks] = (wm2 * 64 + mi * 16 + l15) * 64 +
                   (((ks << 2) + quad) ^ (l15 & 7)) * 8;
#pragma unroll
  for (int ni = 0; ni < 2; ni++)
#pragma unroll
    for (int ks = 0; ks < 2; ks++)
      br[ni][ks] = (wn4 * 32 + ni * 16 + l15) * 64 +
                   (((ks << 2) + quad) ^ (l15 & 7)) * 8;

#define SA(BUF, MH, kb) { \
    cp16(Ab + aoff + (uint)(MH) * 64 * K + (kb), \
         lA + (BUF) * 16384 + (MH) * 8192 + wq); \
    cp16(Ab + aoff + (uint)(MH) * 64 * K + l2off + (kb), \
         lA + (BUF) * 16384 + (MH) * 8192 + 4096 + wq); }
#define SB(BUF, NH, kb) { \
    cp16(Bb + boff + (uint)(NH) * 32 * K + (kb), \
         lB + (BUF) * 16384 + (NH) * 8192 + wq); \
    cp16(Bb + boff + (uint)(NH) * 32 * K + l2off + (kb), \
         lB + (BUF) * 16384 + (NH) * 8192 + 4096 + wq); }
#define RDA(BUF, MH) { _Pragma("unroll") for (int mi = 0; mi < 4; mi++) { \
    _Pragma("unroll") for (int ks = 0; ks < 2; ks++) \
      af[mi][ks] = *(const f16x8*)(lA + (BUF) * 16384 + (MH) * 8192 + ar[mi][ks]); } }
#define RDB(BUF, NH, BF) { _Pragma("unroll") for (int ni = 0; ni < 2; ni++) { \
    _Pragma("unroll") for (int ks = 0; ks < 2; ks++) \
      BF[ni][ks] = *(const f16x8*)(lB + (BUF) * 16384 + (NH) * 8192 + br[ni][ks]); } }
#define MMQ(MH, NH, BF) { __builtin_amdgcn_s_setprio(1); \
    _Pragma("unroll") for (int ks = 0; ks < 2; ks++) { \
      _Pragma("unroll") for (int mi = 0; mi < 4; mi++) { \
        _Pragma("unroll") for (int ni = 0; ni < 2; ni++) \
          acc[(MH) * 4 + mi][(NH) * 2 + ni] = \
              mfma_f16(af[mi][ks], BF[ni][ks], acc[(MH) * 4 + mi][(NH) * 2 + ni]); } } \
    __builtin_amdgcn_s_setprio(0); }
#define PHX(RD, STG, MM, VMW) { RD STG BARR MM VMW BARR }

  f16x8 af[4][2], b0[2][2], b1[2][2];

  // prologue: buf0 = tile0 (4 HT), buf1 = tile1 (A0,B0,B1); VM6 => buf0 ok
  SA(0, 0, 0) SB(0, 0, 0) SB(0, 1, 0) SA(0, 1, 0)
  SA(1, 0, 64) SB(1, 0, 64) SB(1, 1, 64)
  VM6
  BARR

  for (int i = 0; i < iters - 1; i++) {
    const int kA = (2 * i + 1) * 64;
    const int kB = (2 * i + 2) * 64;
    const int kC = (2 * i + 3) * 64;
    PHX(RDA(0, 0) RDB(0, 0, b0), SA(1, 1, kA), MMQ(0, 0, b0), )
    PHX(RDB(0, 1, b1),           SA(0, 0, kB), MMQ(0, 1, b1), )
    PHX(RDA(0, 1),               SB(0, 0, kB), MMQ(1, 0, b0), )
    PHX(,                        SB(0, 1, kB), MMQ(1, 1, b1), VM6)
    PHX(RDA(1, 0) RDB(1, 0, b0), SA(0, 1, kB), MMQ(0, 0, b0), )
    PHX(RDB(1, 1, b1),           SA(1, 0, kC), MMQ(0, 1, b1), )
    PHX(RDA(1, 1),               SB(1, 0, kC), MMQ(1, 0, b0), )
    PHX(,                        SB(1, 1, kC), MMQ(1, 1, b1), VM6)
  }
  {  // peeled last iteration: only b1.A1 (K-64) remains to stage
    PHX(RDA(0, 0) RDB(0, 0, b0), SA(1, 1, K - 64), MMQ(0, 0, b0), )
    PHX(RDB(0, 1, b1),           ,                 MMQ(0, 1, b1), )
    PHX(RDA(0, 1),               ,                 MMQ(1, 0, b0), )
    PHX(,                        ,                 MMQ(1, 1, b1), VM0)
    PHX(RDA(1, 0) RDB(1, 0, b0), ,                 MMQ(0, 0, b0), )
    PHX(RDB(1, 1, b1),           ,                 MMQ(0, 1, b1), )
    PHX(RDA(1, 1),               ,                 MMQ(1, 0, b0), )
    PHX(,                        ,                 MMQ(1, 1, b1), )
  }
#undef SA
#undef SB
#undef RDA
#undef RDB
#undef MMQ
#undef PHX
}

// ---- R3 half-K-ring 8-phase core (512 thr, 4Mx2N waves) — CONTROL --------
// Ring of 4 half-K slots (256x32, 16KB) per matrix; read-ahead regs;
// VM4 every 2 phases (3-4 phase leads). Measured 89.4us on gemm_qk (R3).
__device__ __forceinline__ void core8ph(
    const f16_t* __restrict__ Ab, const f16_t* __restrict__ Bb,
    int m0, int n0, int K, int iters, f32x4 (&acc)[4][8]) {
  __shared__ f16_t lA[32768];
  __shared__ f16_t lB[32768];

  const int tid = threadIdx.x;
  const int w = tid >> 6, lane = tid & 63;
  const int quad = lane >> 4, l15 = lane & 15;
  const int wm = w >> 1, wn = w & 1;
  const int srow = lane >> 2;
  const int sg = (lane & 3) ^ ((lane >> 3) & 3);

  const uint aoff0 = (uint)(m0 + w * 32 + srow) * K + sg * 8;
  const uint aoff1 = aoff0 + 16 * K;
  const uint boff0 = (uint)(n0 + w * 32 + srow) * K + sg * 8;
  const uint boff1 = boff0 + 16 * K;
  const int ld0 = (w * 32) * 32;
  const int ld1 = (w * 32 + 16) * 32;

  int afo[4], bfo[8];
  const int swz = (quad ^ ((l15 >> 1) & 3)) * 8;
#pragma unroll
  for (int mi = 0; mi < 4; mi++) afo[mi] = (wm * 64 + mi * 16 + l15) * 32 + swz;
#pragma unroll
  for (int ni = 0; ni < 8; ni++) bfo[ni] = (wn * 128 + ni * 16 + l15) * 32 + swz;

#define STG_A(sl, kb) { cp16(Ab + aoff0 + (kb), lA + (sl) * 8192 + ld0); \
                        cp16(Ab + aoff1 + (kb), lA + (sl) * 8192 + ld1); }
#define STG_B(sl, kb) { cp16(Bb + boff0 + (kb), lB + (sl) * 8192 + ld0); \
                        cp16(Bb + boff1 + (kb), lB + (sl) * 8192 + ld1); }
#define RD_AF(dst, SL) { _Pragma("unroll") for (int mi = 0; mi < 4; mi++) \
      dst[mi] = *(const f16x8*)(lA + (SL) * 8192 + afo[mi]); }
#define RD_B03(dst, SL) { _Pragma("unroll") for (int ni = 0; ni < 4; ni++) \
      dst[ni] = *(const f16x8*)(lB + (SL) * 8192 + bfo[ni]); }
#define RD_B47(dst, SL) { _Pragma("unroll") for (int ni = 0; ni < 4; ni++) \
      dst[ni] = *(const f16x8*)(lB + (SL) * 8192 + bfo[ni + 4]); }
#define MM_Q0(ar, br) { __builtin_amdgcn_s_setprio(1); \
    _Pragma("unroll") for (int mi = 0; mi < 4; mi++) { \
      _Pragma("unroll") for (int nj = 0; nj < 4; nj++) \
        acc[mi][nj] = mfma_f16(ar[mi], br[nj], acc[mi][nj]); } \
    __builtin_amdgcn_s_setprio(0); }
#define MM_Q1(ar, br) { __builtin_amdgcn_s_setprio(1); \
    _Pragma("unroll") for (int mi = 0; mi < 4; mi++) { \
      _Pragma("unroll") for (int nj = 0; nj < 4; nj++) \
        acc[mi][4 + nj] = mfma_f16(ar[mi], br[nj], acc[mi][4 + nj]); } \
    __builtin_amdgcn_s_setprio(0); }

  f16x8 afA[4], afB[4], b0A[4], b0B[4], b47[4];

  STG_A(0, 0) STG_B(0, 0)
  STG_A(1, 32) STG_B(1, 32)
  STG_A(2, 64) STG_B(2, 64)
  VM4
  BARR
  RD_AF(afA, 0) RD_B03(b0A, 0)

  for (int i = 0; i < iters - 1; i++) {
    const int t0 = 2 * i;
    const int kb3 = (t0 + 1) * 64 + 32;
    const int kb0 = (t0 + 2) * 64;
    const int kb1 = kb0 + 32;
    const int kb2 = (t0 + 3) * 64;
    /*p0*/ RD_B47(b47, 0) STG_A(3, kb3) MM_Q0(afA, b0A) VM4 BARR
    /*p1*/ RD_AF(afB, 1) RD_B03(b0B, 1) STG_B(3, kb3) MM_Q1(afA, b47) BARR
    /*p2*/ RD_B47(b47, 1) STG_A(0, kb0) MM_Q0(afB, b0B) VM4 BARR
    /*p3*/ RD_AF(afA, 2) RD_B03(b0A, 2) STG_B(0, kb0) MM_Q1(afB, b47) BARR
    /*p4*/ RD_B47(b47, 2) STG_A(1, kb1) MM_Q0(afA, b0A) VM4 BARR
    /*p5*/ RD_AF(afB, 3) RD_B03(b0B, 3) STG_B(1, kb1) MM_Q1(afA, b47) BARR
    /*p6*/ RD_B47(b47, 3) STG_A(2, kb2) MM_Q0(afB, b0B) VM4 BARR
    /*p7*/ RD_AF(afA, 0) RD_B03(b0A, 0) STG_B(2, kb2) MM_Q1(afB, b47) BARR
  }
  {
    const int kbp = K - 32;
    /*p0*/ RD_B47(b47, 0) STG_A(3, kbp) MM_Q0(afA, b0A) VM4 BARR
    /*p1*/ RD_AF(afB, 1) RD_B03(b0B, 1) STG_B(3, kbp) MM_Q1(afA, b47) BARR
    /*p2*/ RD_B47(b47, 1) MM_Q0(afB, b0B) VM4 BARR
    /*p3*/ RD_AF(afA, 2) RD_B03(b0A, 2) MM_Q1(afB, b47) BARR
    /*p4*/ RD_B47(b47, 2) MM_Q0(afA, b0A) VM0 BARR
    /*p5*/ RD_AF(afB, 3) RD_B03(b0B, 3) MM_Q1(afA, b47) BARR
    /*p6*/ RD_B47(b47, 3) MM_Q0(afB, b0B) BARR
    /*p7*/ MM_Q1(afB, b47)
  }
#undef STG_A
#undef STG_B
#undef RD_AF
#undef RD_B03
#undef RD_B47
#undef MM_Q0
#undef MM_Q1
}

// ---- 4-phase read-ahead 256x128 GEMM core (512 thr, 4Mx2N waves) ----------
__device__ __forceinline__ void core4ph(
    const f16_t* __restrict__ Ab, const f16_t* __restrict__ Bb,
    int m0, int n0, int K, int iters, f32x4 (&acc)[4][4]) {
  __shared__ f16_t lA[32768];   // 4 x 256x32
  __shared__ f16_t lB[16384];   // 4 x 128x32

  const int tid = threadIdx.x;
  const int w = tid >> 6, lane = tid & 63;
  const int quad = lane >> 4, l15 = lane & 15;
  const int wm = w >> 1, wn = w & 1;
  const int sg = (lane & 3) ^ ((lane >> 3) & 3);

  const uint arow = (uint)(w * 16 + (lane >> 2));
  const uint aoff0 = (uint)(m0 + arow) * K + sg * 8;
  const uint aoff1 = aoff0 + 128 * K;
  const uint boff  = (uint)(n0 + arow) * K + sg * 8;
  const int ldw = w * 512;

  int afo[4], bfo[4];
  const int swz = (quad ^ ((l15 >> 1) & 3)) * 8;
#pragma unroll
  for (int mi = 0; mi < 4; mi++) afo[mi] = (wm * 64 + mi * 16 + l15) * 32 + swz;
#pragma unroll
  for (int ni = 0; ni < 4; ni++) bfo[ni] = (wn * 64 + ni * 16 + l15) * 32 + swz;

#define STG4(sl, kb) { cp16(Ab + aoff0 + (kb), lA + (sl) * 8192 + ldw); \
                       cp16(Ab + aoff1 + (kb), lA + (sl) * 8192 + 4096 + ldw); \
                       cp16(Bb + boff  + (kb), lB + (sl) * 4096 + ldw); }
#define RD4(adst, bdst, SL) { \
    _Pragma("unroll") for (int mi = 0; mi < 4; mi++) \
      adst[mi] = *(const f16x8*)(lA + (SL) * 8192 + afo[mi]); \
    _Pragma("unroll") for (int ni = 0; ni < 4; ni++) \
      bdst[ni] = *(const f16x8*)(lB + (SL) * 4096 + bfo[ni]); }
#define MM4(ar, br) { __builtin_amdgcn_s_setprio(1); \
    _Pragma("unroll") for (int mi = 0; mi < 4; mi++) { \
      _Pragma("unroll") for (int ni = 0; ni < 4; ni++) \
        acc[mi][ni] = mfma_f16(ar[mi], br[ni], acc[mi][ni]); } \
    __builtin_amdgcn_s_setprio(0); }

  f16x8 afA[4], afB[4], bfA[4], bfB[4];

  STG4(0, 0)
  STG4(1, 32)
  STG4(2, 64)
  VM3
  BARR
  RD4(afA, bfA, 0)

  for (int i = 0; i < iters - 1; i++) {
    const int t0 = 2 * i;
    /*p0*/ RD4(afB, bfB, 1) STG4(3, (t0 + 1) * 64 + 32) MM4(afA, bfA) VM3 BARR
    /*p1*/ RD4(afA, bfA, 2) STG4(0, (t0 + 2) * 64) MM4(afB, bfB) VM3 BARR
    /*p2*/ RD4(afB, bfB, 3) STG4(1, (t0 + 2) * 64 + 32) MM4(afA, bfA) VM3 BARR
    /*p3*/ RD4(afA, bfA, 0) STG4(2, (t0 + 3) * 64) MM4(afB, bfB) VM3 BARR
  }
  {
    /*p0*/ RD4(afB, bfB, 1) STG4(3, K - 32) MM4(afA, bfA) VM3 BARR
    /*p1*/ RD4(afA, bfA, 2) MM4(afB, bfB) VM0 BARR
    /*p2*/ RD4(afB, bfB, 3) MM4(afA, bfA) BARR
    /*p3*/ MM4(afB, bfB)
  }
#undef STG4
#undef RD4
#undef MM4
}

// ---- 256x256-tile projection GEMM (R3 ring core): C = (A B^T + b)*scale ----
__global__ __launch_bounds__(512, 2) void gemm512(
    const f16_t* __restrict__ A, const f16_t* __restrict__ B,
    f16_t* __restrict__ C, const float* __restrict__ bias0,
    const float* __restrict__ bias1, int K,
    long sAz, long sBz, long sCz, float scale0, float scale1, int Cstride) {
  const int bz = blockIdx.z;
  const int n0 = blockIdx.x * 256;
  const int m0 = blockIdx.y * 256;
  const f16_t* Ab = A + (size_t)sAz * bz;
  const f16_t* Bb = B + (size_t)sBz * bz;

  f32x4 acc[4][8] = {};
  core8ph(Ab, Bb, m0, n0, K, K >> 7, acc);

  const int tid = threadIdx.x;
  const int w = tid >> 6, lane = tid & 63;
  const int quad = lane >> 4, l15 = lane & 15;
  const int wm = w >> 1, wn = w & 1;
  const float* bias = bz ? bias1 : bias0;
  const float scale = bz ? scale1 : scale0;
  f16_t* Cb = C + (size_t)sCz * bz;
#pragma unroll
  for (int mi = 0; mi < 4; mi++) {
#pragma unroll
    for (int ni = 0; ni < 8; ni++) {
      const int gm0 = m0 + wm * 64 + mi * 16 + quad * 4;
      const int gn = n0 + wn * 128 + ni * 16 + l15;
#pragma unroll
      for (int r = 0; r < 4; r++) {
        const int gm = gm0 + r;
        Cb[(size_t)gm * Cstride + gn] = (f16_t)((acc[mi][ni][r] + bias[gn]) * scale);
      }
    }
  }
}

// ---- v^T projection, 256x128 4-phase core: C[gn>>12][gm][gn&4095] ----
__global__ __launch_bounds__(512, 2) void gemm256(
    const f16_t* __restrict__ A, const f16_t* __restrict__ B,
    f16_t* __restrict__ C, const float* __restrict__ bias0, int K) {
  const int n0 = blockIdx.x * 128;
  const int m0 = blockIdx.y * 256;

  f32x4 acc[4][4] = {};
  core4ph(A, B, m0, n0, K, K >> 7, acc);

  const int tid = threadIdx.x;
  const int w = tid >> 6, lane = tid & 63;
  const int quad = lane >> 4, l15 = lane & 15;
  const int wm = w >> 1, wn = w & 1;
#pragma unroll
  for (int mi = 0; mi < 4; mi++) {
#pragma unroll
    for (int ni = 0; ni < 4; ni++) {
      const int gm0 = m0 + wm * 64 + mi * 16 + quad * 4;
      const int gn = n0 + wn * 64 + ni * 16 + l15;
#pragma unroll
      for (int r = 0; r < 4; r++) {
        const int gm = gm0 + r;
        const int bb = gn >> 12;
        const int s = gn & 4095;
        C[(size_t)bb * 4194304 + (size_t)gm * 4096 + s] =
            (f16_t)(acc[mi][ni][r] + bias0[gm]);
      }
    }
  }
}

// ---- QK^T 256x256, depth-3 template core, XCD-remapped + softmax ----
__global__ __launch_bounds__(512, 2) void gemm_qk(
    const f16_t* __restrict__ A, const f16_t* __restrict__ B,
    f16_t* __restrict__ S, const u64* __restrict__ mb,
    float* __restrict__ lrow) {
  // bijective XCD remap: each XCD owns 2 m-tiles x 16 n-tiles x 2 bz
  const int bid = blockIdx.x;
  const int xcd = bid & 7;
  const int l = bid >> 3;
  const int bz = l >> 5;
  const int r5 = l & 31;
  const int m0 = (xcd * 2 + (r5 >> 4)) * 256;
  const int n0 = (r5 & 15) * 256;
  const f16_t* Ab = A + (size_t)4194304 * bz;
  const f16_t* Bb = B + (size_t)4194304 * bz;

  f32x4 acc[8][4] = {};
  core8x(Ab, Bb, m0, n0, 1024, 8, acc);

  // epilogue: p = exp(s-3) masked (bitmask), store f16, row sums -> atomicAdd
  const int tid = threadIdx.x;
  const int w = tid >> 6, lane = tid & 63;
  const int quad = lane >> 4, l15 = lane & 15;
  const int wm2 = w >> 2, wn4 = w & 3;
  f16_t* Sb = S + (size_t)16777216 * bz;
  float* lb = lrow + bz * 4096;
  const int wword = (n0 >> 6) + wn4;
#pragma unroll
  for (int mi = 0; mi < 8; mi++) {
#pragma unroll
    for (int r = 0; r < 4; r++) {
      const int gm = m0 + wm2 * 128 + mi * 16 + quad * 4 + r;
      const u64 mw = mb[(size_t)gm * 64 + wword];
      float rs = 0.f;
#pragma unroll
      for (int ni = 0; ni < 4; ni++) {
        const int col_l = ni * 16 + l15;
        const int bit = (int)((mw >> col_l) & 1);
        const float p = bit ? 0.f : __expf(acc[mi][ni][r] - 3.0f);
        Sb[(size_t)gm * 4096 + n0 + wn4 * 64 + col_l] = (f16_t)p;
        rs += p;
      }
      rs += __shfl_xor(rs, 1); rs += __shfl_xor(rs, 2);
      rs += __shfl_xor(rs, 4); rs += __shfl_xor(rs, 8);
      if (l15 == 0) atomicAdd(&lb[gm], rs);
    }
  }
}

// ---- PV GEMM 256x128, K=4096, 4-phase core, XCD-remapped: O=(S' vt)/l ----
__global__ __launch_bounds__(512, 2) void gemm_pv(
    const f16_t* __restrict__ S, const f16_t* __restrict__ V,
    float* __restrict__ O, const float* __restrict__ lrow) {
  const int bid = blockIdx.x;          // 256 blocks = 1/CU
  const int xcd = bid & 7;
  const int l = bid >> 3;
  const int bz = l >> 4;
  const int r4 = l & 15;
  const int m0 = (xcd * 2 + (r4 >> 3)) * 256;
  const int n0 = (r4 & 7) * 128;

  const f16_t* Ab = S + (size_t)16777216 * bz;
  const f16_t* Bb = V + (size_t)4194304 * bz;

  f32x4 acc[4][4] = {};
  core4ph(Ab, Bb, m0, n0, 4096, 32, acc);

  const int tid = threadIdx.x;
  const int w = tid >> 6, lane = tid & 63;
  const int quad = lane >> 4, l15 = lane & 15;
  const int wm = w >> 1, wn = w & 1;
  float* Ob = O + (size_t)4194304 * bz;
  const float* lb = lrow + bz * 4096;
#pragma unroll
  for (int mi = 0; mi < 4; mi++) {
#pragma unroll
    for (int ni = 0; ni < 4; ni++) {
      const int gm0 = m0 + wm * 64 + mi * 16 + quad * 4;
      const int gn = n0 + wn * 64 + ni * 16 + l15;
#pragma unroll
      for (int r = 0; r < 4; r++) {
        const int gm = gm0 + r;
        Ob[(size_t)gm * 1024 + gn] = acc[mi][ni][r] * (1.0f / lb[gm]);
      }
    }
  }
}

// ======================= launch =======================
extern "C" void kernel_launch(void* const* d_in, const int* in_sizes, int n_in,
                              void* d_out, int out_size, void* d_ws, size_t ws_size,
                              hipStream_t stream) {
  const float* query = (const float*)d_in[0];
  const float* key_  = (const float*)d_in[1];
  const float* value = (const float*)d_in[2];
  const int* mask    = (const int*)d_in[3];
  const float* Wq = (const float*)d_in[4];
  const float* bq = (const float*)d_in[5];
  const float* Wk = (const float*)d_in[6];
  const float* bk = (const float*)d_in[7];
  const float* Wv = (const float*)d_in[8];
  const float* bv = (const float*)d_in[9];
  float* out = (float*)d_out;

  const size_t MB = (size_t)1 << 20;
  char* w = (char*)d_ws;
  f16_t* qb  = (f16_t*)(w);
  f16_t* kb  = (f16_t*)(w + 16 * MB);
  f16_t* vt  = (f16_t*)(w + 32 * MB);
  f16_t* xq  = (f16_t*)(w + 48 * MB);
  f16_t* xk  = (f16_t*)(w + 64 * MB);
  f16_t* xv  = (f16_t*)(w + 80 * MB);
  f16_t* wqh = (f16_t*)(w + 96 * MB);
  f16_t* wkh = (f16_t*)(w + 98 * MB);
  f16_t* wvh = (f16_t*)(w + 100 * MB);
  f16_t* S   = (f16_t*)(w + 48 * MB);   // overlaps x/W after projections
  float* ls  = (float*)(w + 112 * MB);
  u64* mb = (u64*)d_out;                 // dead until PV writes out

  cvt_mask<<<dim3(4096, 7), 256, 0, stream>>>(query, key_, value, Wq, Wk, Wv,
                                              mask, xq, xk, xv, wqh, wkh, wvh, mb);
  // q & k projections fused (z=2), 256x256 tile: q scaled by 1/32 (exact pow2)
  gemm512<<<dim3(4, 32, 2), 512, 0, stream>>>(
      xq, wqh, qb, bq, bk, 1024, 8388608L, 1048576L, 8388608L,
      0.03125f, 1.0f, 1024);
  // v^T: A=Wv [1024xK], B=xv [8192xK] -> vt[b][e][s]
  gemm256<<<dim3(64, 4), 512, 0, stream>>>(wvh, xv, vt, bv, 1024);
  hipMemsetAsync(ls, 0, 2 * 4096 * sizeof(float), stream);
  // S' = exp(qk^T - 3) masked, l row sums
  gemm_qk<<<dim3(512), 512, 0, stream>>>(qb, kb, S, mb, ls);
  // O = S' vt / l
  gemm_pv<<<dim3(256), 512, 0, stream>>>(S, vt, out, ls);
}

// Round 6
// 462.352 us; speedup vs baseline: 1.0089x; 1.0089x over previous
//
#include <hip/hip_runtime.h>
#include <hip/hip_bf16.h>

// B=2, S=4096, E=1024 attention + QKV projections, all-fp16 MFMA pipeline:
//   cvt_mask  fp32->fp16 q,k,v,W* + mask -> 2MB bitmask (in d_out head)
//   gemm512   z=2: q/k projections, 256x256, R3 half-K-ring core
//   gemm256   v^T projection, 256x128 4-phase core
//   gemm_qk_r bz=0: 256x256 ring core (CONTROL, known ~44.7us/round)
//   gemm_qk_m bz=1: 128x128 m97-style core (EXPERIMENT): 256thr, 32KB LDS,
//             single-buffer, 2 barriers/K-step, 3 blocks/CU -> TLP hides drain
//   gemm_pv   256x128 tile, 4-phase core, K=4096: O = (S' vt) / l
//
// Round-6: same-work A/B duel on the two qk halves + full dispatch-budget
// reveal (top-5 now shows pv/g512/g256/cvt instead of 5x qk).

typedef _Float16 f16_t;
typedef _Float16 f16x8 __attribute__((ext_vector_type(8)));
typedef float f32x4 __attribute__((ext_vector_type(4)));
typedef unsigned long long u64;
typedef unsigned int uint;

union PackH8 { f16x8 v; f16_t e[8]; };

__device__ __forceinline__ f32x4 mfma_f16(f16x8 a, f16x8 b, f32x4 c) {
  return __builtin_amdgcn_mfma_f32_16x16x32_f16(a, b, c, 0, 0, 0);
}

__device__ __forceinline__ void cp16(const f16_t* g, f16_t* l) {
  __builtin_amdgcn_global_load_lds(
      (const __attribute__((address_space(1))) unsigned int*)g,
      (__attribute__((address_space(3))) unsigned int*)l, 16, 0, 0);
}

// ---- fp32 -> fp16 bulk convert (y=0..5) + mask bitpack (y=6) ----
__global__ __launch_bounds__(256) void cvt_mask(
    const float* __restrict__ q, const float* __restrict__ k,
    const float* __restrict__ v, const float* __restrict__ wq,
    const float* __restrict__ wk, const float* __restrict__ wv,
    const int* __restrict__ mask,
    f16_t* __restrict__ xq, f16_t* __restrict__ xk, f16_t* __restrict__ xv,
    f16_t* __restrict__ wqh, f16_t* __restrict__ wkh, f16_t* __restrict__ wvh,
    u64* __restrict__ mb) {
  if (blockIdx.y == 6) {
    const int lane = threadIdx.x & 63;
    int wid = blockIdx.x * 4 + (threadIdx.x >> 6);
    for (int w = wid; w < 262144; w += 16384) {
      const int pred = mask[(size_t)w * 64 + lane] != 0;
      u64 b = __ballot(pred);
      if (lane == 0) mb[w] = b;
    }
    return;
  }
  const float* src; f16_t* dst; size_t n;
  switch (blockIdx.y) {
    case 0: src = q;  dst = xq;  n = 8388608; break;
    case 1: src = k;  dst = xk;  n = 8388608; break;
    case 2: src = v;  dst = xv;  n = 8388608; break;
    case 3: src = wq; dst = wqh; n = 1048576; break;
    case 4: src = wk; dst = wkh; n = 1048576; break;
    default: src = wv; dst = wvh; n = 1048576; break;
  }
  size_t i = ((size_t)blockIdx.x * 256 + threadIdx.x) * 8;
  if (i >= n) return;
  float4 a = *(const float4*)(src + i);
  float4 b = *(const float4*)(src + i + 4);
  PackH8 p;
  p.e[0] = (f16_t)a.x; p.e[1] = (f16_t)a.y; p.e[2] = (f16_t)a.z; p.e[3] = (f16_t)a.w;
  p.e[4] = (f16_t)b.x; p.e[5] = (f16_t)b.y; p.e[6] = (f16_t)b.z; p.e[7] = (f16_t)b.w;
  *(f16x8*)(dst + i) = p.v;
}

#define BARR { asm volatile("" ::: "memory"); __builtin_amdgcn_s_barrier(); }
#define VM0 asm volatile("s_waitcnt vmcnt(0)" ::: "memory");
#define VM3 asm volatile("s_waitcnt vmcnt(3)" ::: "memory");
#define VM4 asm volatile("s_waitcnt vmcnt(4)" ::: "memory");

// ---- R3 half-K-ring 8-phase 256x256 core (512 thr, 4Mx2N waves) ----------
// Ring of 4 half-K slots (256x32, 16KB) per matrix; read-ahead regs;
// VM4 every 2 phases (3-4 phase leads). Measured 89.4us on gemm_qk (R3).
__device__ __forceinline__ void core8ph(
    const f16_t* __restrict__ Ab, const f16_t* __restrict__ Bb,
    int m0, int n0, int K, int iters, f32x4 (&acc)[4][8]) {
  __shared__ f16_t lA[32768];
  __shared__ f16_t lB[32768];

  const int tid = threadIdx.x;
  const int w = tid >> 6, lane = tid & 63;
  const int quad = lane >> 4, l15 = lane & 15;
  const int wm = w >> 1, wn = w & 1;
  const int srow = lane >> 2;
  const int sg = (lane & 3) ^ ((lane >> 3) & 3);

  const uint aoff0 = (uint)(m0 + w * 32 + srow) * K + sg * 8;
  const uint aoff1 = aoff0 + 16 * K;
  const uint boff0 = (uint)(n0 + w * 32 + srow) * K + sg * 8;
  const uint boff1 = boff0 + 16 * K;
  const int ld0 = (w * 32) * 32;
  const int ld1 = (w * 32 + 16) * 32;

  int afo[4], bfo[8];
  const int swz = (quad ^ ((l15 >> 1) & 3)) * 8;
#pragma unroll
  for (int mi = 0; mi < 4; mi++) afo[mi] = (wm * 64 + mi * 16 + l15) * 32 + swz;
#pragma unroll
  for (int ni = 0; ni < 8; ni++) bfo[ni] = (wn * 128 + ni * 16 + l15) * 32 + swz;

#define STG_A(sl, kb) { cp16(Ab + aoff0 + (kb), lA + (sl) * 8192 + ld0); \
                        cp16(Ab + aoff1 + (kb), lA + (sl) * 8192 + ld1); }
#define STG_B(sl, kb) { cp16(Bb + boff0 + (kb), lB + (sl) * 8192 + ld0); \
                        cp16(Bb + boff1 + (kb), lB + (sl) * 8192 + ld1); }
#define RD_AF(dst, SL) { _Pragma("unroll") for (int mi = 0; mi < 4; mi++) \
      dst[mi] = *(const f16x8*)(lA + (SL) * 8192 + afo[mi]); }
#define RD_B03(dst, SL) { _Pragma("unroll") for (int ni = 0; ni < 4; ni++) \
      dst[ni] = *(const f16x8*)(lB + (SL) * 8192 + bfo[ni]); }
#define RD_B47(dst, SL) { _Pragma("unroll") for (int ni = 0; ni < 4; ni++) \
      dst[ni] = *(const f16x8*)(lB + (SL) * 8192 + bfo[ni + 4]); }
#define MM_Q0(ar, br) { __builtin_amdgcn_s_setprio(1); \
    _Pragma("unroll") for (int mi = 0; mi < 4; mi++) { \
      _Pragma("unroll") for (int nj = 0; nj < 4; nj++) \
        acc[mi][nj] = mfma_f16(ar[mi], br[nj], acc[mi][nj]); } \
    __builtin_amdgcn_s_setprio(0); }
#define MM_Q1(ar, br) { __builtin_amdgcn_s_setprio(1); \
    _Pragma("unroll") for (int mi = 0; mi < 4; mi++) { \
      _Pragma("unroll") for (int nj = 0; nj < 4; nj++) \
        acc[mi][4 + nj] = mfma_f16(ar[mi], br[nj], acc[mi][4 + nj]); } \
    __builtin_amdgcn_s_setprio(0); }

  f16x8 afA[4], afB[4], b0A[4], b0B[4], b47[4];

  STG_A(0, 0) STG_B(0, 0)
  STG_A(1, 32) STG_B(1, 32)
  STG_A(2, 64) STG_B(2, 64)
  VM4
  BARR
  RD_AF(afA, 0) RD_B03(b0A, 0)

  for (int i = 0; i < iters - 1; i++) {
    const int t0 = 2 * i;
    const int kb3 = (t0 + 1) * 64 + 32;
    const int kb0 = (t0 + 2) * 64;
    const int kb1 = kb0 + 32;
    const int kb2 = (t0 + 3) * 64;
    /*p0*/ RD_B47(b47, 0) STG_A(3, kb3) MM_Q0(afA, b0A) VM4 BARR
    /*p1*/ RD_AF(afB, 1) RD_B03(b0B, 1) STG_B(3, kb3) MM_Q1(afA, b47) BARR
    /*p2*/ RD_B47(b47, 1) STG_A(0, kb0) MM_Q0(afB, b0B) VM4 BARR
    /*p3*/ RD_AF(afA, 2) RD_B03(b0A, 2) STG_B(0, kb0) MM_Q1(afB, b47) BARR
    /*p4*/ RD_B47(b47, 2) STG_A(1, kb1) MM_Q0(afA, b0A) VM4 BARR
    /*p5*/ RD_AF(afB, 3) RD_B03(b0B, 3) STG_B(1, kb1) MM_Q1(afA, b47) BARR
    /*p6*/ RD_B47(b47, 3) STG_A(2, kb2) MM_Q0(afB, b0B) VM4 BARR
    /*p7*/ RD_AF(afA, 0) RD_B03(b0A, 0) STG_B(2, kb2) MM_Q1(afB, b47) BARR
  }
  {
    const int kbp = K - 32;
    /*p0*/ RD_B47(b47, 0) STG_A(3, kbp) MM_Q0(afA, b0A) VM4 BARR
    /*p1*/ RD_AF(afB, 1) RD_B03(b0B, 1) STG_B(3, kbp) MM_Q1(afA, b47) BARR
    /*p2*/ RD_B47(b47, 1) MM_Q0(afB, b0B) VM4 BARR
    /*p3*/ RD_AF(afA, 2) RD_B03(b0A, 2) MM_Q1(afB, b47) BARR
    /*p4*/ RD_B47(b47, 2) MM_Q0(afA, b0A) VM0 BARR
    /*p5*/ RD_AF(afB, 3) RD_B03(b0B, 3) MM_Q1(afA, b47) BARR
    /*p6*/ RD_B47(b47, 3) MM_Q0(afB, b0B) BARR
    /*p7*/ MM_Q1(afB, b47)
  }
#undef STG_A
#undef STG_B
#undef RD_AF
#undef RD_B03
#undef RD_B47
#undef MM_Q0
#undef MM_Q1
}

// ---- 4-phase read-ahead 256x128 GEMM core (512 thr, 4Mx2N waves) ----------
__device__ __forceinline__ void core4ph(
    const f16_t* __restrict__ Ab, const f16_t* __restrict__ Bb,
    int m0, int n0, int K, int iters, f32x4 (&acc)[4][4]) {
  __shared__ f16_t lA[32768];   // 4 x 256x32
  __shared__ f16_t lB[16384];   // 4 x 128x32

  const int tid = threadIdx.x;
  const int w = tid >> 6, lane = tid & 63;
  const int quad = lane >> 4, l15 = lane & 15;
  const int wm = w >> 1, wn = w & 1;
  const int sg = (lane & 3) ^ ((lane >> 3) & 3);

  const uint arow = (uint)(w * 16 + (lane >> 2));
  const uint aoff0 = (uint)(m0 + arow) * K + sg * 8;
  const uint aoff1 = aoff0 + 128 * K;
  const uint boff  = (uint)(n0 + arow) * K + sg * 8;
  const int ldw = w * 512;

  int afo[4], bfo[4];
  const int swz = (quad ^ ((l15 >> 1) & 3)) * 8;
#pragma unroll
  for (int mi = 0; mi < 4; mi++) afo[mi] = (wm * 64 + mi * 16 + l15) * 32 + swz;
#pragma unroll
  for (int ni = 0; ni < 4; ni++) bfo[ni] = (wn * 64 + ni * 16 + l15) * 32 + swz;

#define STG4(sl, kb) { cp16(Ab + aoff0 + (kb), lA + (sl) * 8192 + ldw); \
                       cp16(Ab + aoff1 + (kb), lA + (sl) * 8192 + 4096 + ldw); \
                       cp16(Bb + boff  + (kb), lB + (sl) * 4096 + ldw); }
#define RD4(adst, bdst, SL) { \
    _Pragma("unroll") for (int mi = 0; mi < 4; mi++) \
      adst[mi] = *(const f16x8*)(lA + (SL) * 8192 + afo[mi]); \
    _Pragma("unroll") for (int ni = 0; ni < 4; ni++) \
      bdst[ni] = *(const f16x8*)(lB + (SL) * 4096 + bfo[ni]); }
#define MM4(ar, br) { __builtin_amdgcn_s_setprio(1); \
    _Pragma("unroll") for (int mi = 0; mi < 4; mi++) { \
      _Pragma("unroll") for (int ni = 0; ni < 4; ni++) \
        acc[mi][ni] = mfma_f16(ar[mi], br[ni], acc[mi][ni]); } \
    __builtin_amdgcn_s_setprio(0); }

  f16x8 afA[4], afB[4], bfA[4], bfB[4];

  STG4(0, 0)
  STG4(1, 32)
  STG4(2, 64)
  VM3
  BARR
  RD4(afA, bfA, 0)

  for (int i = 0; i < iters - 1; i++) {
    const int t0 = 2 * i;
    /*p0*/ RD4(afB, bfB, 1) STG4(3, (t0 + 1) * 64 + 32) MM4(afA, bfA) VM3 BARR
    /*p1*/ RD4(afA, bfA, 2) STG4(0, (t0 + 2) * 64) MM4(afB, bfB) VM3 BARR
    /*p2*/ RD4(afB, bfB, 3) STG4(1, (t0 + 2) * 64 + 32) MM4(afA, bfA) VM3 BARR
    /*p3*/ RD4(afA, bfA, 0) STG4(2, (t0 + 3) * 64) MM4(afB, bfB) VM3 BARR
  }
  {
    /*p0*/ RD4(afB, bfB, 1) STG4(3, K - 32) MM4(afA, bfA) VM3 BARR
    /*p1*/ RD4(afA, bfA, 2) MM4(afB, bfB) VM0 BARR
    /*p2*/ RD4(afB, bfB, 3) MM4(afA, bfA) BARR
    /*p3*/ MM4(afB, bfB)
  }
#undef STG4
#undef RD4
#undef MM4
}

// ---- 256x256-tile projection GEMM (ring core): C = (A B^T + b)*scale ----
__global__ __launch_bounds__(512, 2) void gemm512(
    const f16_t* __restrict__ A, const f16_t* __restrict__ B,
    f16_t* __restrict__ C, const float* __restrict__ bias0,
    const float* __restrict__ bias1, int K,
    long sAz, long sBz, long sCz, float scale0, float scale1, int Cstride) {
  const int bz = blockIdx.z;
  const int n0 = blockIdx.x * 256;
  const int m0 = blockIdx.y * 256;
  const f16_t* Ab = A + (size_t)sAz * bz;
  const f16_t* Bb = B + (size_t)sBz * bz;

  f32x4 acc[4][8] = {};
  core8ph(Ab, Bb, m0, n0, K, K >> 7, acc);

  const int tid = threadIdx.x;
  const int w = tid >> 6, lane = tid & 63;
  const int quad = lane >> 4, l15 = lane & 15;
  const int wm = w >> 1, wn = w & 1;
  const float* bias = bz ? bias1 : bias0;
  const float scale = bz ? scale1 : scale0;
  f16_t* Cb = C + (size_t)sCz * bz;
#pragma unroll
  for (int mi = 0; mi < 4; mi++) {
#pragma unroll
    for (int ni = 0; ni < 8; ni++) {
      const int gm0 = m0 + wm * 64 + mi * 16 + quad * 4;
      const int gn = n0 + wn * 128 + ni * 16 + l15;
#pragma unroll
      for (int r = 0; r < 4; r++) {
        const int gm = gm0 + r;
        Cb[(size_t)gm * Cstride + gn] = (f16_t)((acc[mi][ni][r] + bias[gn]) * scale);
      }
    }
  }
}

// ---- v^T projection, 256x128 4-phase core: C[gn>>12][gm][gn&4095] ----
__global__ __launch_bounds__(512, 2) void gemm256(
    const f16_t* __restrict__ A, const f16_t* __restrict__ B,
    f16_t* __restrict__ C, const float* __restrict__ bias0, int K) {
  const int n0 = blockIdx.x * 128;
  const int m0 = blockIdx.y * 256;

  f32x4 acc[4][4] = {};
  core4ph(A, B, m0, n0, K, K >> 7, acc);

  const int tid = threadIdx.x;
  const int w = tid >> 6, lane = tid & 63;
  const int quad = lane >> 4, l15 = lane & 15;
  const int wm = w >> 1, wn = w & 1;
#pragma unroll
  for (int mi = 0; mi < 4; mi++) {
#pragma unroll
    for (int ni = 0; ni < 4; ni++) {
      const int gm0 = m0 + wm * 64 + mi * 16 + quad * 4;
      const int gn = n0 + wn * 64 + ni * 16 + l15;
#pragma unroll
      for (int r = 0; r < 4; r++) {
        const int gm = gm0 + r;
        const int bb = gn >> 12;
        const int s = gn & 4095;
        C[(size_t)bb * 4194304 + (size_t)gm * 4096 + s] =
            (f16_t)(acc[mi][ni][r] + bias0[gm]);
      }
    }
  }
}

// ---- QK^T bz=0: 256x256 ring core, XCD-remapped (CONTROL) ----
__global__ __launch_bounds__(512, 2) void gemm_qk_r(
    const f16_t* __restrict__ A, const f16_t* __restrict__ B,
    f16_t* __restrict__ S, const u64* __restrict__ mb,
    float* __restrict__ lrow) {
  const int bid = blockIdx.x;          // 256 blocks
  const int xcd = bid & 7;
  const int l = bid >> 3;              // 0..31
  const int m0 = (xcd * 2 + (l >> 4)) * 256;
  const int n0 = (l & 15) * 256;

  f32x4 acc[4][8] = {};
  core8ph(A, B, m0, n0, 1024, 8, acc);

  const int tid = threadIdx.x;
  const int w = tid >> 6, lane = tid & 63;
  const int quad = lane >> 4, l15 = lane & 15;
  const int wm = w >> 1, wn = w & 1;
  const int wbase = (n0 >> 6) + wn * 2;
#pragma unroll
  for (int mi = 0; mi < 4; mi++) {
#pragma unroll
    for (int r = 0; r < 4; r++) {
      const int gm = m0 + wm * 64 + mi * 16 + quad * 4 + r;
      const u64 w0 = mb[(size_t)gm * 64 + wbase];
      const u64 w1 = mb[(size_t)gm * 64 + wbase + 1];
      float rs = 0.f;
#pragma unroll
      for (int ni = 0; ni < 8; ni++) {
        const int col_l = ni * 16 + l15;
        const u64 mw = (ni < 4) ? w0 : w1;
        const int bit = (int)((mw >> (col_l & 63)) & 1);
        const float p = bit ? 0.f : __expf(acc[mi][ni][r] - 3.0f);
        S[(size_t)gm * 4096 + n0 + wn * 128 + col_l] = (f16_t)p;
        rs += p;
      }
      rs += __shfl_xor(rs, 1); rs += __shfl_xor(rs, 2);
      rs += __shfl_xor(rs, 4); rs += __shfl_xor(rs, 8);
      if (l15 == 0) atomicAdd(&lrow[gm], rs);
    }
  }
}

// ---- QK^T bz=1: 128x128 m97-style core (EXPERIMENT) ----------------------
// 256 thr (4 waves, wave-tile 64x64, acc[4][4]=64 VGPR); LDS 32KB single-
// buffer (A,B 128x64); per K-step: sync / stage 8 cp16/thread-row / VM0 /
// sync / 16 ds_read / 32 MFMA. 3 blocks/CU (launch_bounds(256,3)) -> other
// blocks' MFMAs hide this block's barrier drain (m97 mechanism, 912 TF bf16).
__global__ __launch_bounds__(256, 3) void gemm_qk_m(
    const f16_t* __restrict__ A, const f16_t* __restrict__ B,
    f16_t* __restrict__ S, const u64* __restrict__ mb,
    float* __restrict__ lrow) {
  __shared__ f16_t sA[8192];
  __shared__ f16_t sB[8192];
  const int bid = blockIdx.x;          // 1024 blocks: 32m x 32n, XCD-chunked
  const int xcd = bid & 7;
  const int l = bid >> 3;              // 0..127
  const int m0 = (xcd * 4 + (l >> 5)) * 128;
  const int n0 = (l & 31) * 128;
  const f16_t* Ab = A + 4194304;       // bz=1
  const f16_t* Bb = B + 4194304;
  const int K = 1024;

  const int tid = threadIdx.x;
  const int w = tid >> 6, lane = tid & 63;
  const int quad = lane >> 4, l15 = lane & 15;
  const int wm = w >> 1, wn = w & 1;

  // staging: wave w stages chunks c in {w,w+4,w+8,w+12}; chunk c = rows
  // 8c..8c+7 x 64k (1KB). lane covers row 8c+(lane>>3), phys col-grp lane&7
  // holding logical k-grp (lane&7)^(row&7). LDS dest linear: c*512 elems.
  const int srow = lane >> 3;               // row&7
  const int sg = (lane & 7) ^ srow;         // pre-swizzled global col-grp

  // fragment reads: row = (wm|wn)*64 + mi*16 + l15; phys grp = logical^(row&7)
  int ar[4][2], br[4][2];
#pragma unroll
  for (int mi = 0; mi < 4; mi++)
#pragma unroll
    for (int ks = 0; ks < 2; ks++) {
      ar[mi][ks] = (wm * 64 + mi * 16 + l15) * 64 +
                   (((ks << 2) + quad) ^ (l15 & 7)) * 8;
      br[mi][ks] = (wn * 64 + mi * 16 + l15) * 64 +
                   (((ks << 2) + quad) ^ (l15 & 7)) * 8;
    }

  f32x4 acc[4][4] = {};

  for (int k0 = 0; k0 < K; k0 += 64) {
    __syncthreads();                        // WAR: all reads of prev tile done
#pragma unroll
    for (int j = 0; j < 4; j++) {
      const int c = j * 4 + w;
      cp16(Ab + (uint)(m0 + c * 8 + srow) * K + sg * 8 + k0, sA + c * 512);
      cp16(Bb + (uint)(n0 + c * 8 + srow) * K + sg * 8 + k0, sB + c * 512);
    }
    VM0
    __syncthreads();                        // tile visible to all waves
    f16x8 af[4][2], bf[4][2];
#pragma unroll
    for (int mi = 0; mi < 4; mi++)
#pragma unroll
      for (int ks = 0; ks < 2; ks++) {
        af[mi][ks] = *(const f16x8*)(sA + ar[mi][ks]);
        bf[mi][ks] = *(const f16x8*)(sB + br[mi][ks]);
      }
    __builtin_amdgcn_s_setprio(1);
#pragma unroll
    for (int ks = 0; ks < 2; ks++)
#pragma unroll
      for (int mi = 0; mi < 4; mi++)
#pragma unroll
        for (int ni = 0; ni < 4; ni++)
          acc[mi][ni] = mfma_f16(af[mi][ks], bf[ni][ks], acc[mi][ni]);
    __builtin_amdgcn_s_setprio(0);
  }

  // epilogue: p = exp(s-3) masked, store f16, row sums -> atomicAdd (bz=1)
  f16_t* Sb = S + (size_t)16777216;
  float* lb = lrow + 4096;
  const int wword = (n0 >> 6) + wn;
#pragma unroll
  for (int mi = 0; mi < 4; mi++) {
#pragma unroll
    for (int r = 0; r < 4; r++) {
      const int gm = m0 + wm * 64 + mi * 16 + quad * 4 + r;
      const u64 mw = mb[(size_t)gm * 64 + wword];
      float rs = 0.f;
#pragma unroll
      for (int ni = 0; ni < 4; ni++) {
        const int col_l = ni * 16 + l15;
        const int bit = (int)((mw >> col_l) & 1);
        const float p = bit ? 0.f : __expf(acc[mi][ni][r] - 3.0f);
        Sb[(size_t)gm * 4096 + n0 + wn * 64 + col_l] = (f16_t)p;
        rs += p;
      }
      rs += __shfl_xor(rs, 1); rs += __shfl_xor(rs, 2);
      rs += __shfl_xor(rs, 4); rs += __shfl_xor(rs, 8);
      if (l15 == 0) atomicAdd(&lb[gm], rs);
    }
  }
}

// ---- PV GEMM 256x128, K=4096, 4-phase core, XCD-remapped: O=(S' vt)/l ----
__global__ __launch_bounds__(512, 2) void gemm_pv(
    const f16_t* __restrict__ S, const f16_t* __restrict__ V,
    float* __restrict__ O, const float* __restrict__ lrow) {
  const int bid = blockIdx.x;          // 256 blocks = 1/CU
  const int xcd = bid & 7;
  const int l = bid >> 3;
  const int bz = l >> 4;
  const int r4 = l & 15;
  const int m0 = (xcd * 2 + (r4 >> 3)) * 256;
  const int n0 = (r4 & 7) * 128;

  const f16_t* Ab = S + (size_t)16777216 * bz;
  const f16_t* Bb = V + (size_t)4194304 * bz;

  f32x4 acc[4][4] = {};
  core4ph(Ab, Bb, m0, n0, 4096, 32, acc);

  const int tid = threadIdx.x;
  const int w = tid >> 6, lane = tid & 63;
  const int quad = lane >> 4, l15 = lane & 15;
  const int wm = w >> 1, wn = w & 1;
  float* Ob = O + (size_t)4194304 * bz;
  const float* lb = lrow + bz * 4096;
#pragma unroll
  for (int mi = 0; mi < 4; mi++) {
#pragma unroll
    for (int ni = 0; ni < 4; ni++) {
      const int gm0 = m0 + wm * 64 + mi * 16 + quad * 4;
      const int gn = n0 + wn * 64 + ni * 16 + l15;
#pragma unroll
      for (int r = 0; r < 4; r++) {
        const int gm = gm0 + r;
        Ob[(size_t)gm * 1024 + gn] = acc[mi][ni][r] * (1.0f / lb[gm]);
      }
    }
  }
}

// ======================= launch =======================
extern "C" void kernel_launch(void* const* d_in, const int* in_sizes, int n_in,
                              void* d_out, int out_size, void* d_ws, size_t ws_size,
                              hipStream_t stream) {
  const float* query = (const float*)d_in[0];
  const float* key_  = (const float*)d_in[1];
  const float* value = (const float*)d_in[2];
  const int* mask    = (const int*)d_in[3];
  const float* Wq = (const float*)d_in[4];
  const float* bq = (const float*)d_in[5];
  const float* Wk = (const float*)d_in[6];
  const float* bk = (const float*)d_in[7];
  const float* Wv = (const float*)d_in[8];
  const float* bv = (const float*)d_in[9];
  float* out = (float*)d_out;

  const size_t MB = (size_t)1 << 20;
  char* w = (char*)d_ws;
  f16_t* qb  = (f16_t*)(w);
  f16_t* kb  = (f16_t*)(w + 16 * MB);
  f16_t* vt  = (f16_t*)(w + 32 * MB);
  f16_t* xq  = (f16_t*)(w + 48 * MB);
  f16_t* xk  = (f16_t*)(w + 64 * MB);
  f16_t* xv  = (f16_t*)(w + 80 * MB);
  f16_t* wqh = (f16_t*)(w + 96 * MB);
  f16_t* wkh = (f16_t*)(w + 98 * MB);
  f16_t* wvh = (f16_t*)(w + 100 * MB);
  f16_t* S   = (f16_t*)(w + 48 * MB);   // overlaps x/W after projections
  float* ls  = (float*)(w + 112 * MB);
  u64* mb = (u64*)d_out;                 // dead until PV writes out

  cvt_mask<<<dim3(4096, 7), 256, 0, stream>>>(query, key_, value, Wq, Wk, Wv,
                                              mask, xq, xk, xv, wqh, wkh, wvh, mb);
  // q & k projections fused (z=2), 256x256 tile: q scaled by 1/32 (exact pow2)
  gemm512<<<dim3(4, 32, 2), 512, 0, stream>>>(
      xq, wqh, qb, bq, bk, 1024, 8388608L, 1048576L, 8388608L,
      0.03125f, 1.0f, 1024);
  // v^T: A=Wv [1024xK], B=xv [8192xK] -> vt[b][e][s]
  gemm256<<<dim3(64, 4), 512, 0, stream>>>(wvh, xv, vt, bv, 1024);
  hipMemsetAsync(ls, 0, 2 * 4096 * sizeof(float), stream);
  // S' = exp(qk^T - 3) masked, l row sums — bz split: ring vs m97 A/B
  gemm_qk_r<<<dim3(256), 512, 0, stream>>>(qb, kb, S, mb, ls);
  gemm_qk_m<<<dim3(1024), 256, 0, stream>>>(qb, kb, S, mb, ls);
  // O = S' vt / l
  gemm_pv<<<dim3(256), 512, 0, stream>>>(S, vt, out, ls);
}

// Round 7
// 436.766 us; speedup vs baseline: 1.0681x; 1.0586x over previous
//
#include <hip/hip_runtime.h>
#include <hip/hip_bf16.h>

// B=2, S=4096, E=1024 attention + QKV projections, all-fp16 MFMA pipeline:
//   cvt_mask  fp32->fp16 q,k,v,W* + mask -> 2MB bitmask (flat grid, no dead blocks)
//   gemm512   z=2: q/k projections, 256x256, ring core (772 TF measured)
//   gemm256   v^T projection, 256x128 4-phase core (control)
//   gemm_qk   256x256 ring core, XCD-remapped (known 89.4us)
//   gemm_pv   EXPERIMENT: 128x128 m97-style, 256thr, 32KB LDS, 512 blocks
//             -> 2 independent blocks/CU (cross-block TLP hides barrier drain)
//
// Round-7: pv re-tiled to the guide's best-measured simple structure
// (128^2 @ >=2 blk/CU = 912 TF class at K=4096). qk_m verdict from R6:
// m97-style at K=1024 = ~490 TF -> ring stays for all K=1024 GEMMs.

typedef _Float16 f16_t;
typedef _Float16 f16x8 __attribute__((ext_vector_type(8)));
typedef float f32x4 __attribute__((ext_vector_type(4)));
typedef unsigned long long u64;
typedef unsigned int uint;

union PackH8 { f16x8 v; f16_t e[8]; };

__device__ __forceinline__ f32x4 mfma_f16(f16x8 a, f16x8 b, f32x4 c) {
  return __builtin_amdgcn_mfma_f32_16x16x32_f16(a, b, c, 0, 0, 0);
}

__device__ __forceinline__ void cp16(const f16_t* g, f16_t* l) {
  __builtin_amdgcn_global_load_lds(
      (const __attribute__((address_space(1))) unsigned int*)g,
      (__attribute__((address_space(3))) unsigned int*)l, 16, 0, 0);
}

// ---- fp32 -> fp16 bulk convert + mask bitpack, flat 1-D grid -------------
// blocks 0..12287: q/k/v (4096 each); 12288..13823: wq/wk/wv (512 each);
// 13824..17919: mask bitpack (4096).
__global__ __launch_bounds__(256) void cvt_mask(
    const float* __restrict__ q, const float* __restrict__ k,
    const float* __restrict__ v, const float* __restrict__ wq,
    const float* __restrict__ wk, const float* __restrict__ wv,
    const int* __restrict__ mask,
    f16_t* __restrict__ xq, f16_t* __restrict__ xk, f16_t* __restrict__ xv,
    f16_t* __restrict__ wqh, f16_t* __restrict__ wkh, f16_t* __restrict__ wvh,
    u64* __restrict__ mb) {
  const int bid = blockIdx.x;
  if (bid >= 13824) {
    const int lane = threadIdx.x & 63;
    int wid = (bid - 13824) * 4 + (threadIdx.x >> 6);
    for (int w = wid; w < 262144; w += 16384) {
      const int pred = mask[(size_t)w * 64 + lane] != 0;
      u64 b = __ballot(pred);
      if (lane == 0) mb[w] = b;
    }
    return;
  }
  const float* src; f16_t* dst; int rb;
  if (bid < 12288) {
    rb = bid & 4095;
    switch (bid >> 12) {
      case 0: src = q; dst = xq; break;
      case 1: src = k; dst = xk; break;
      default: src = v; dst = xv; break;
    }
  } else {
    rb = (bid - 12288) & 511;
    switch ((bid - 12288) >> 9) {
      case 0: src = wq; dst = wqh; break;
      case 1: src = wk; dst = wkh; break;
      default: src = wv; dst = wvh; break;
    }
  }
  size_t i = ((size_t)rb * 256 + threadIdx.x) * 8;
  float4 a = *(const float4*)(src + i);
  float4 b = *(const float4*)(src + i + 4);
  PackH8 p;
  p.e[0] = (f16_t)a.x; p.e[1] = (f16_t)a.y; p.e[2] = (f16_t)a.z; p.e[3] = (f16_t)a.w;
  p.e[4] = (f16_t)b.x; p.e[5] = (f16_t)b.y; p.e[6] = (f16_t)b.z; p.e[7] = (f16_t)b.w;
  *(f16x8*)(dst + i) = p.v;
}

#define BARR { asm volatile("" ::: "memory"); __builtin_amdgcn_s_barrier(); }
#define VM0 asm volatile("s_waitcnt vmcnt(0)" ::: "memory");
#define VM3 asm volatile("s_waitcnt vmcnt(3)" ::: "memory");
#define VM4 asm volatile("s_waitcnt vmcnt(4)" ::: "memory");

// ---- R3 half-K-ring 8-phase 256x256 core (512 thr, 4Mx2N waves) ----------
// Ring of 4 half-K slots (256x32, 16KB) per matrix; read-ahead regs;
// VM4 every 2 phases (3-4 phase leads). Measured 89.4us on gemm_qk.
__device__ __forceinline__ void core8ph(
    const f16_t* __restrict__ Ab, const f16_t* __restrict__ Bb,
    int m0, int n0, int K, int iters, f32x4 (&acc)[4][8]) {
  __shared__ f16_t lA[32768];
  __shared__ f16_t lB[32768];

  const int tid = threadIdx.x;
  const int w = tid >> 6, lane = tid & 63;
  const int quad = lane >> 4, l15 = lane & 15;
  const int wm = w >> 1, wn = w & 1;
  const int srow = lane >> 2;
  const int sg = (lane & 3) ^ ((lane >> 3) & 3);

  const uint aoff0 = (uint)(m0 + w * 32 + srow) * K + sg * 8;
  const uint aoff1 = aoff0 + 16 * K;
  const uint boff0 = (uint)(n0 + w * 32 + srow) * K + sg * 8;
  const uint boff1 = boff0 + 16 * K;
  const int ld0 = (w * 32) * 32;
  const int ld1 = (w * 32 + 16) * 32;

  int afo[4], bfo[8];
  const int swz = (quad ^ ((l15 >> 1) & 3)) * 8;
#pragma unroll
  for (int mi = 0; mi < 4; mi++) afo[mi] = (wm * 64 + mi * 16 + l15) * 32 + swz;
#pragma unroll
  for (int ni = 0; ni < 8; ni++) bfo[ni] = (wn * 128 + ni * 16 + l15) * 32 + swz;

#define STG_A(sl, kb) { cp16(Ab + aoff0 + (kb), lA + (sl) * 8192 + ld0); \
                        cp16(Ab + aoff1 + (kb), lA + (sl) * 8192 + ld1); }
#define STG_B(sl, kb) { cp16(Bb + boff0 + (kb), lB + (sl) * 8192 + ld0); \
                        cp16(Bb + boff1 + (kb), lB + (sl) * 8192 + ld1); }
#define RD_AF(dst, SL) { _Pragma("unroll") for (int mi = 0; mi < 4; mi++) \
      dst[mi] = *(const f16x8*)(lA + (SL) * 8192 + afo[mi]); }
#define RD_B03(dst, SL) { _Pragma("unroll") for (int ni = 0; ni < 4; ni++) \
      dst[ni] = *(const f16x8*)(lB + (SL) * 8192 + bfo[ni]); }
#define RD_B47(dst, SL) { _Pragma("unroll") for (int ni = 0; ni < 4; ni++) \
      dst[ni] = *(const f16x8*)(lB + (SL) * 8192 + bfo[ni + 4]); }
#define MM_Q0(ar, br) { __builtin_amdgcn_s_setprio(1); \
    _Pragma("unroll") for (int mi = 0; mi < 4; mi++) { \
      _Pragma("unroll") for (int nj = 0; nj < 4; nj++) \
        acc[mi][nj] = mfma_f16(ar[mi], br[nj], acc[mi][nj]); } \
    __builtin_amdgcn_s_setprio(0); }
#define MM_Q1(ar, br) { __builtin_amdgcn_s_setprio(1); \
    _Pragma("unroll") for (int mi = 0; mi < 4; mi++) { \
      _Pragma("unroll") for (int nj = 0; nj < 4; nj++) \
        acc[mi][4 + nj] = mfma_f16(ar[mi], br[nj], acc[mi][4 + nj]); } \
    __builtin_amdgcn_s_setprio(0); }

  f16x8 afA[4], afB[4], b0A[4], b0B[4], b47[4];

  STG_A(0, 0) STG_B(0, 0)
  STG_A(1, 32) STG_B(1, 32)
  STG_A(2, 64) STG_B(2, 64)
  VM4
  BARR
  RD_AF(afA, 0) RD_B03(b0A, 0)

  for (int i = 0; i < iters - 1; i++) {
    const int t0 = 2 * i;
    const int kb3 = (t0 + 1) * 64 + 32;
    const int kb0 = (t0 + 2) * 64;
    const int kb1 = kb0 + 32;
    const int kb2 = (t0 + 3) * 64;
    /*p0*/ RD_B47(b47, 0) STG_A(3, kb3) MM_Q0(afA, b0A) VM4 BARR
    /*p1*/ RD_AF(afB, 1) RD_B03(b0B, 1) STG_B(3, kb3) MM_Q1(afA, b47) BARR
    /*p2*/ RD_B47(b47, 1) STG_A(0, kb0) MM_Q0(afB, b0B) VM4 BARR
    /*p3*/ RD_AF(afA, 2) RD_B03(b0A, 2) STG_B(0, kb0) MM_Q1(afB, b47) BARR
    /*p4*/ RD_B47(b47, 2) STG_A(1, kb1) MM_Q0(afA, b0A) VM4 BARR
    /*p5*/ RD_AF(afB, 3) RD_B03(b0B, 3) STG_B(1, kb1) MM_Q1(afA, b47) BARR
    /*p6*/ RD_B47(b47, 3) STG_A(2, kb2) MM_Q0(afB, b0B) VM4 BARR
    /*p7*/ RD_AF(afA, 0) RD_B03(b0A, 0) STG_B(2, kb2) MM_Q1(afB, b47) BARR
  }
  {
    const int kbp = K - 32;
    /*p0*/ RD_B47(b47, 0) STG_A(3, kbp) MM_Q0(afA, b0A) VM4 BARR
    /*p1*/ RD_AF(afB, 1) RD_B03(b0B, 1) STG_B(3, kbp) MM_Q1(afA, b47) BARR
    /*p2*/ RD_B47(b47, 1) MM_Q0(afB, b0B) VM4 BARR
    /*p3*/ RD_AF(afA, 2) RD_B03(b0A, 2) MM_Q1(afB, b47) BARR
    /*p4*/ RD_B47(b47, 2) MM_Q0(afA, b0A) VM0 BARR
    /*p5*/ RD_AF(afB, 3) RD_B03(b0B, 3) MM_Q1(afA, b47) BARR
    /*p6*/ RD_B47(b47, 3) MM_Q0(afB, b0B) BARR
    /*p7*/ MM_Q1(afB, b47)
  }
#undef STG_A
#undef STG_B
#undef RD_AF
#undef RD_B03
#undef RD_B47
#undef MM_Q0
#undef MM_Q1
}

// ---- 4-phase read-ahead 256x128 GEMM core (512 thr, 4Mx2N waves) ----------
__device__ __forceinline__ void core4ph(
    const f16_t* __restrict__ Ab, const f16_t* __restrict__ Bb,
    int m0, int n0, int K, int iters, f32x4 (&acc)[4][4]) {
  __shared__ f16_t lA[32768];   // 4 x 256x32
  __shared__ f16_t lB[16384];   // 4 x 128x32

  const int tid = threadIdx.x;
  const int w = tid >> 6, lane = tid & 63;
  const int quad = lane >> 4, l15 = lane & 15;
  const int wm = w >> 1, wn = w & 1;
  const int sg = (lane & 3) ^ ((lane >> 3) & 3);

  const uint arow = (uint)(w * 16 + (lane >> 2));
  const uint aoff0 = (uint)(m0 + arow) * K + sg * 8;
  const uint aoff1 = aoff0 + 128 * K;
  const uint boff  = (uint)(n0 + arow) * K + sg * 8;
  const int ldw = w * 512;

  int afo[4], bfo[4];
  const int swz = (quad ^ ((l15 >> 1) & 3)) * 8;
#pragma unroll
  for (int mi = 0; mi < 4; mi++) afo[mi] = (wm * 64 + mi * 16 + l15) * 32 + swz;
#pragma unroll
  for (int ni = 0; ni < 4; ni++) bfo[ni] = (wn * 64 + ni * 16 + l15) * 32 + swz;

#define STG4(sl, kb) { cp16(Ab + aoff0 + (kb), lA + (sl) * 8192 + ldw); \
                       cp16(Ab + aoff1 + (kb), lA + (sl) * 8192 + 4096 + ldw); \
                       cp16(Bb + boff  + (kb), lB + (sl) * 4096 + ldw); }
#define RD4(adst, bdst, SL) { \
    _Pragma("unroll") for (int mi = 0; mi < 4; mi++) \
      adst[mi] = *(const f16x8*)(lA + (SL) * 8192 + afo[mi]); \
    _Pragma("unroll") for (int ni = 0; ni < 4; ni++) \
      bdst[ni] = *(const f16x8*)(lB + (SL) * 4096 + bfo[ni]); }
#define MM4(ar, br) { __builtin_amdgcn_s_setprio(1); \
    _Pragma("unroll") for (int mi = 0; mi < 4; mi++) { \
      _Pragma("unroll") for (int ni = 0; ni < 4; ni++) \
        acc[mi][ni] = mfma_f16(ar[mi], br[ni], acc[mi][ni]); } \
    __builtin_amdgcn_s_setprio(0); }

  f16x8 afA[4], afB[4], bfA[4], bfB[4];

  STG4(0, 0)
  STG4(1, 32)
  STG4(2, 64)
  VM3
  BARR
  RD4(afA, bfA, 0)

  for (int i = 0; i < iters - 1; i++) {
    const int t0 = 2 * i;
    /*p0*/ RD4(afB, bfB, 1) STG4(3, (t0 + 1) * 64 + 32) MM4(afA, bfA) VM3 BARR
    /*p1*/ RD4(afA, bfA, 2) STG4(0, (t0 + 2) * 64) MM4(afB, bfB) VM3 BARR
    /*p2*/ RD4(afB, bfB, 3) STG4(1, (t0 + 2) * 64 + 32) MM4(afA, bfA) VM3 BARR
    /*p3*/ RD4(afA, bfA, 0) STG4(2, (t0 + 3) * 64) MM4(afB, bfB) VM3 BARR
  }
  {
    /*p0*/ RD4(afB, bfB, 1) STG4(3, K - 32) MM4(afA, bfA) VM3 BARR
    /*p1*/ RD4(afA, bfA, 2) MM4(afB, bfB) VM0 BARR
    /*p2*/ RD4(afB, bfB, 3) MM4(afA, bfA) BARR
    /*p3*/ MM4(afB, bfB)
  }
#undef STG4
#undef RD4
#undef MM4
}

// ---- 256x256-tile projection GEMM (ring core): C = (A B^T + b)*scale ----
__global__ __launch_bounds__(512, 2) void gemm512(
    const f16_t* __restrict__ A, const f16_t* __restrict__ B,
    f16_t* __restrict__ C, const float* __restrict__ bias0,
    const float* __restrict__ bias1, int K,
    long sAz, long sBz, long sCz, float scale0, float scale1, int Cstride) {
  const int bz = blockIdx.z;
  const int n0 = blockIdx.x * 256;
  const int m0 = blockIdx.y * 256;
  const f16_t* Ab = A + (size_t)sAz * bz;
  const f16_t* Bb = B + (size_t)sBz * bz;

  f32x4 acc[4][8] = {};
  core8ph(Ab, Bb, m0, n0, K, K >> 7, acc);

  const int tid = threadIdx.x;
  const int w = tid >> 6, lane = tid & 63;
  const int quad = lane >> 4, l15 = lane & 15;
  const int wm = w >> 1, wn = w & 1;
  const float* bias = bz ? bias1 : bias0;
  const float scale = bz ? scale1 : scale0;
  f16_t* Cb = C + (size_t)sCz * bz;
#pragma unroll
  for (int mi = 0; mi < 4; mi++) {
#pragma unroll
    for (int ni = 0; ni < 8; ni++) {
      const int gm0 = m0 + wm * 64 + mi * 16 + quad * 4;
      const int gn = n0 + wn * 128 + ni * 16 + l15;
#pragma unroll
      for (int r = 0; r < 4; r++) {
        const int gm = gm0 + r;
        Cb[(size_t)gm * Cstride + gn] = (f16_t)((acc[mi][ni][r] + bias[gn]) * scale);
      }
    }
  }
}

// ---- v^T projection, 256x128 4-phase core: C[gn>>12][gm][gn&4095] ----
__global__ __launch_bounds__(512, 2) void gemm256(
    const f16_t* __restrict__ A, const f16_t* __restrict__ B,
    f16_t* __restrict__ C, const float* __restrict__ bias0, int K) {
  const int n0 = blockIdx.x * 128;
  const int m0 = blockIdx.y * 256;

  f32x4 acc[4][4] = {};
  core4ph(A, B, m0, n0, K, K >> 7, acc);

  const int tid = threadIdx.x;
  const int w = tid >> 6, lane = tid & 63;
  const int quad = lane >> 4, l15 = lane & 15;
  const int wm = w >> 1, wn = w & 1;
#pragma unroll
  for (int mi = 0; mi < 4; mi++) {
#pragma unroll
    for (int ni = 0; ni < 4; ni++) {
      const int gm0 = m0 + wm * 64 + mi * 16 + quad * 4;
      const int gn = n0 + wn * 64 + ni * 16 + l15;
#pragma unroll
      for (int r = 0; r < 4; r++) {
        const int gm = gm0 + r;
        const int bb = gn >> 12;
        const int s = gn & 4095;
        C[(size_t)bb * 4194304 + (size_t)gm * 4096 + s] =
            (f16_t)(acc[mi][ni][r] + bias0[gm]);
      }
    }
  }
}

// ---- QK^T 256x256 ring core, XCD-remapped + constant-max softmax ----
__global__ __launch_bounds__(512, 2) void gemm_qk(
    const f16_t* __restrict__ A, const f16_t* __restrict__ B,
    f16_t* __restrict__ S, const u64* __restrict__ mb,
    float* __restrict__ lrow) {
  const int bid = blockIdx.x;          // 512 blocks
  const int xcd = bid & 7;
  const int l = bid >> 3;
  const int bz = l >> 5;
  const int r5 = l & 31;
  const int m0 = (xcd * 2 + (r5 >> 4)) * 256;
  const int n0 = (r5 & 15) * 256;
  const f16_t* Ab = A + (size_t)4194304 * bz;
  const f16_t* Bb = B + (size_t)4194304 * bz;

  f32x4 acc[4][8] = {};
  core8ph(Ab, Bb, m0, n0, 1024, 8, acc);

  const int tid = threadIdx.x;
  const int w = tid >> 6, lane = tid & 63;
  const int quad = lane >> 4, l15 = lane & 15;
  const int wm = w >> 1, wn = w & 1;
  f16_t* Sb = S + (size_t)16777216 * bz;
  float* lb = lrow + bz * 4096;
  const int wbase = (n0 >> 6) + wn * 2;
#pragma unroll
  for (int mi = 0; mi < 4; mi++) {
#pragma unroll
    for (int r = 0; r < 4; r++) {
      const int gm = m0 + wm * 64 + mi * 16 + quad * 4 + r;
      const u64 w0 = mb[(size_t)gm * 64 + wbase];
      const u64 w1 = mb[(size_t)gm * 64 + wbase + 1];
      float rs = 0.f;
#pragma unroll
      for (int ni = 0; ni < 8; ni++) {
        const int col_l = ni * 16 + l15;
        const u64 mw = (ni < 4) ? w0 : w1;
        const int bit = (int)((mw >> (col_l & 63)) & 1);
        const float p = bit ? 0.f : __expf(acc[mi][ni][r] - 3.0f);
        Sb[(size_t)gm * 4096 + n0 + wn * 128 + col_l] = (f16_t)p;
        rs += p;
      }
      rs += __shfl_xor(rs, 1); rs += __shfl_xor(rs, 2);
      rs += __shfl_xor(rs, 4); rs += __shfl_xor(rs, 8);
      if (l15 == 0) atomicAdd(&lb[gm], rs);
    }
  }
}

// ---- PV GEMM: EXPERIMENT — 128x128 m97-style, 256 thr, 32KB LDS ----------
// 512 blocks (32m x 8n x 2bz), XCD-grouped -> 2 independent blocks/CU
// resident (launch_bounds(256,2): VGPR<=256, no spill). Per K-step(64):
// sync / 8 cp16 (pre-swizzled global, linear LDS) / VM0 / sync /
// per-ks {8 ds_read_b128, 16 MFMA}. Cross-block TLP hides the VM0 drain.
__global__ __launch_bounds__(256, 2) void gemm_pv(
    const f16_t* __restrict__ S, const f16_t* __restrict__ V,
    float* __restrict__ O, const float* __restrict__ lrow) {
  __shared__ f16_t sA[8192];   // 128 x 64
  __shared__ f16_t sB[8192];
  const int bid = blockIdx.x;          // 512
  const int xcd = bid & 7;
  const int l = bid >> 3;              // 0..63
  const int bz = l >> 5;
  const int r = l & 31;
  const int m0 = (xcd * 4 + (r >> 3)) * 128;   // 32 m-tiles
  const int n0 = (r & 7) * 128;                // 8 n-tiles
  const f16_t* Ab = S + (size_t)16777216 * bz;
  const f16_t* Bb = V + (size_t)4194304 * bz;

  const int tid = threadIdx.x;
  const int w = tid >> 6, lane = tid & 63;
  const int quad = lane >> 4, l15 = lane & 15;
  const int wm = w >> 1, wn = w & 1;

  // staging: wave w stages chunks c = {w, 4+w, 8+w, 12+w}; chunk c = rows
  // 8c..8c+7 x 64k (1KB). lane: row 8c+(lane>>3); phys col-grp lane&7 holds
  // logical k-grp (lane&7)^(row&7) (pre-swizzled global source).
  const int srow = lane >> 3;
  const int sg = (lane & 7) ^ srow;

  // fragment reads: row = wX*64 + mi*16 + l15; phys grp = logical ^ (row&7)
  int ar[4][2], br[4][2];
#pragma unroll
  for (int mi = 0; mi < 4; mi++)
#pragma unroll
    for (int ks = 0; ks < 2; ks++) {
      ar[mi][ks] = (wm * 64 + mi * 16 + l15) * 64 +
                   (((ks << 2) + quad) ^ (l15 & 7)) * 8;
      br[mi][ks] = (wn * 64 + mi * 16 + l15) * 64 +
                   (((ks << 2) + quad) ^ (l15 & 7)) * 8;
    }

  f32x4 acc[4][4] = {};

  for (int k0 = 0; k0 < 4096; k0 += 64) {
    __syncthreads();                        // prev tile reads complete
#pragma unroll
    for (int j = 0; j < 4; j++) {
      const int c = j * 4 + w;
      cp16(Ab + (uint)(m0 + c * 8 + srow) * 4096 + sg * 8 + k0, sA + c * 512);
      cp16(Bb + (uint)(n0 + c * 8 + srow) * 4096 + sg * 8 + k0, sB + c * 512);
    }
    VM0
    __syncthreads();                        // tile visible
#pragma unroll
    for (int ks = 0; ks < 2; ks++) {
      f16x8 af[4], bf[4];
#pragma unroll
      for (int mi = 0; mi < 4; mi++) {
        af[mi] = *(const f16x8*)(sA + ar[mi][ks]);
        bf[mi] = *(const f16x8*)(sB + br[mi][ks]);
      }
      __builtin_amdgcn_s_setprio(1);
#pragma unroll
      for (int mi = 0; mi < 4; mi++)
#pragma unroll
        for (int ni = 0; ni < 4; ni++)
          acc[mi][ni] = mfma_f16(af[mi], bf[ni], acc[mi][ni]);
      __builtin_amdgcn_s_setprio(0);
    }
  }

  float* Ob = O + (size_t)4194304 * bz;
  const float* lb = lrow + bz * 4096;
#pragma unroll
  for (int mi = 0; mi < 4; mi++) {
#pragma unroll
    for (int ni = 0; ni < 4; ni++) {
      const int gm0 = m0 + wm * 64 + mi * 16 + quad * 4;
      const int gn = n0 + wn * 64 + ni * 16 + l15;
#pragma unroll
      for (int r2 = 0; r2 < 4; r2++) {
        const int gm = gm0 + r2;
        Ob[(size_t)gm * 1024 + gn] = acc[mi][ni][r2] * (1.0f / lb[gm]);
      }
    }
  }
}

// ======================= launch =======================
extern "C" void kernel_launch(void* const* d_in, const int* in_sizes, int n_in,
                              void* d_out, int out_size, void* d_ws, size_t ws_size,
                              hipStream_t stream) {
  const float* query = (const float*)d_in[0];
  const float* key_  = (const float*)d_in[1];
  const float* value = (const float*)d_in[2];
  const int* mask    = (const int*)d_in[3];
  const float* Wq = (const float*)d_in[4];
  const float* bq = (const float*)d_in[5];
  const float* Wk = (const float*)d_in[6];
  const float* bk = (const float*)d_in[7];
  const float* Wv = (const float*)d_in[8];
  const float* bv = (const float*)d_in[9];
  float* out = (float*)d_out;

  const size_t MB = (size_t)1 << 20;
  char* w = (char*)d_ws;
  f16_t* qb  = (f16_t*)(w);
  f16_t* kb  = (f16_t*)(w + 16 * MB);
  f16_t* vt  = (f16_t*)(w + 32 * MB);
  f16_t* xq  = (f16_t*)(w + 48 * MB);
  f16_t* xk  = (f16_t*)(w + 64 * MB);
  f16_t* xv  = (f16_t*)(w + 80 * MB);
  f16_t* wqh = (f16_t*)(w + 96 * MB);
  f16_t* wkh = (f16_t*)(w + 98 * MB);
  f16_t* wvh = (f16_t*)(w + 100 * MB);
  f16_t* S   = (f16_t*)(w + 48 * MB);   // overlaps x/W after projections
  float* ls  = (float*)(w + 112 * MB);
  u64* mb = (u64*)d_out;                 // dead until PV writes out

  cvt_mask<<<dim3(17920), 256, 0, stream>>>(query, key_, value, Wq, Wk, Wv,
                                            mask, xq, xk, xv, wqh, wkh, wvh, mb);
  // q & k projections fused (z=2), 256x256 tile: q scaled by 1/32 (exact pow2)
  gemm512<<<dim3(4, 32, 2), 512, 0, stream>>>(
      xq, wqh, qb, bq, bk, 1024, 8388608L, 1048576L, 8388608L,
      0.03125f, 1.0f, 1024);
  // v^T: A=Wv [1024xK], B=xv [8192xK] -> vt[b][e][s]
  gemm256<<<dim3(64, 4), 512, 0, stream>>>(wvh, xv, vt, bv, 1024);
  hipMemsetAsync(ls, 0, 2 * 4096 * sizeof(float), stream);
  // S' = exp(qk^T - 3) masked, l row sums
  gemm_qk<<<dim3(512), 512, 0, stream>>>(qb, kb, S, mb, ls);
  // O = S' vt / l
  gemm_pv<<<dim3(512), 256, 0, stream>>>(S, vt, out, ls);
}